// Round 5
// baseline (1844.947 us; speedup 1.0000x reference)
//
#include <hip/hip_runtime.h>
#include <hip/hip_cooperative_groups.h>

namespace cg = cooperative_groups;

// GCN 5-layer, no inter-layer nonlinearity -> collapses to rank-6 outer product:
// out = relu( a5*c0^T + u4*c1^T + u3*c2^T + u2*c3^T + u1*c4^T + 1*b5^T )
// a_k = S^k x, u_k = S^k 1, S = D^-1/2 (A + I) D^-1/2 (weighted), x is N x 1.
//
// R5: R4 spent ~90 us in 13 inter-kernel gaps (~7 us each, inferred from
// R2/R3 dispatch sums). Fuse everything into ONE cooperative kernel with
// grid.sync() between phases. Fallback to the R4 multi-kernel path if the
// cooperative launch is rejected.

#define TB 256
#define BNODES 128          // nodes per bucket
#define BMAX 1024           // max buckets in LDS arrays (B = 782)
#define CHB 256             // chunk blocks for fallback hist/place

// ==================== shared device helpers ====================

__device__ __forceinline__ void chains_block(
    const float* __restrict__ W1, const float* __restrict__ b1,
    const float* __restrict__ W2, const float* __restrict__ b2,
    const float* __restrict__ W3, const float* __restrict__ b3,
    const float* __restrict__ W4, const float* __restrict__ b4,
    const float* __restrict__ W5, float* __restrict__ coef,
    float (*A)[112], float (*Bm)[112]) {
    int t = threadIdx.x;
    if (t < 20) { A[0][t] = W1[t]; A[1][t] = b1[t]; }
    __syncthreads();
    if (t < 40) {
        for (int c = 0; c < 2; ++c) {
            float acc = 0.f;
            for (int k = 0; k < 20; ++k) acc += A[c][k] * W2[k * 40 + t];
            Bm[c][t] = acc;
        }
        Bm[2][t] = b2[t];
    }
    __syncthreads();
    if (t < 60) {
        for (int c = 0; c < 3; ++c) {
            float acc = 0.f;
            for (int k = 0; k < 40; ++k) acc += Bm[c][k] * W3[k * 60 + t];
            A[c][t] = acc;
        }
        A[3][t] = b3[t];
    }
    __syncthreads();
    if (t < 80) {
        for (int c = 0; c < 4; ++c) {
            float acc = 0.f;
            for (int k = 0; k < 60; ++k) acc += A[c][k] * W4[k * 80 + t];
            Bm[c][t] = acc;
        }
        Bm[4][t] = b4[t];
    }
    __syncthreads();
    if (t < 100) {
        for (int c = 0; c < 5; ++c) {
            float acc = 0.f;
            for (int k = 0; k < 80; ++k) acc += Bm[c][k] * W5[k * 100 + t];
            coef[c * 100 + t] = acc;
        }
    }
}

// ==================== cooperative mega-kernel ====================

__global__ __launch_bounds__(TB, 4) void k_mega(
    const float* __restrict__ x,
    const int* __restrict__ src, const int* __restrict__ dst,
    const float* __restrict__ w,
    const float* __restrict__ W1, const float* __restrict__ b1,
    const float* __restrict__ W2, const float* __restrict__ b2,
    const float* __restrict__ W3, const float* __restrict__ b3,
    const float* __restrict__ W4, const float* __restrict__ b4,
    const float* __restrict__ W5, const float* __restrict__ b5,
    int* __restrict__ histmat, int* __restrict__ bstart,
    float* __restrict__ dinv, float* __restrict__ selfn,
    float* __restrict__ coef, int2* __restrict__ payload,
    float2* __restrict__ schain, float4* __restrict__ out,
    int n, int E, int B, int chunk)
{
    cg::grid_group grid = cg::this_grid();
    const int tid = threadIdx.x;
    const int blk = blockIdx.x;
    const int G = gridDim.x;   // == B

    __shared__ union {
        int    ihist[BMAX];
        float  wdeg[BNODES];
        float2 sacc[BNODES];
        struct { float A[5][112]; float Bm[5][112]; } ch;
    } u;
    __shared__ int stmp[TB];

    // ---- phase 1: per-chunk LDS histogram -> histmat[bucket*G + blk] ----
    for (int j = tid; j < B; j += TB) u.ihist[j] = 0;
    __syncthreads();
    {
        int e0 = blk * chunk, e1 = min(E, e0 + chunk);
        for (int i = e0 + tid; i < e1; i += TB)
            atomicAdd(&u.ihist[dst[i] >> 7], 1);
    }
    __syncthreads();
    for (int j = tid; j < B; j += TB) histmat[j * G + blk] = u.ihist[j];
    __threadfence();
    grid.sync();

    // ---- phase 2: block j scans bucket-row j in place; total -> bstart[j] ----
    {
        int* row = histmat + (size_t)blk * G;
        int carry = 0;
        for (int base = 0; base < G; base += TB) {
            int i = base + tid;
            int v = (i < G) ? row[i] : 0;
            stmp[tid] = v;
            __syncthreads();
            for (int o = 1; o < TB; o <<= 1) {
                int t = (tid >= o) ? stmp[tid - o] : 0;
                __syncthreads();
                stmp[tid] += t;
                __syncthreads();
            }
            if (i < G) row[i] = carry + stmp[tid] - v;
            carry += stmp[TB - 1];
            __syncthreads();
        }
        if (tid == 0) bstart[blk] = carry;
    }
    __threadfence();
    grid.sync();

    // ---- phase 3: block 0 scans bucket totals; block 1 computes coef ----
    if (blk == 0) {
        int carry = 0;
        for (int base = 0; base < B; base += TB) {
            int i = base + tid;
            int v = (i < B) ? bstart[i] : 0;
            stmp[tid] = v;
            __syncthreads();
            for (int o = 1; o < TB; o <<= 1) {
                int t = (tid >= o) ? stmp[tid - o] : 0;
                __syncthreads();
                stmp[tid] += t;
                __syncthreads();
            }
            if (i < B) bstart[i] = carry + stmp[tid] - v;
            carry += stmp[TB - 1];
            __syncthreads();
        }
        if (tid == 0) bstart[B] = E;
    } else if (blk == 1) {
        chains_block(W1, b1, W2, b2, W3, b3, W4, b4, W5, coef, u.ch.A, u.ch.Bm);
    }
    __threadfence();
    grid.sync();

    // ---- phase 4: place (cursor = scanned row col + bucket start) ----
    for (int j = tid; j < B; j += TB) u.ihist[j] = histmat[(size_t)j * G + blk] + bstart[j];
    __syncthreads();
    {
        int e0 = blk * chunk, e1 = min(E, e0 + chunk);
        for (int i = e0 + tid; i < e1; i += TB) {
            int d = dst[i];
            int j = d >> 7;
            int slot = atomicAdd(&u.ihist[j], 1);
            payload[slot] = make_int2(src[i] | ((d & 127) << 17), __float_as_int(w[i]));
        }
    }
    __threadfence();
    grid.sync();

    // ---- phase 5: per-bucket weighted degree -> dinv, selfn ----
    {
        if (tid < BNODES) u.wdeg[tid] = 0.f;
        __syncthreads();
        int b0 = bstart[blk], b1e = bstart[blk + 1];
        for (int i = b0 + tid; i < b1e; i += TB) {
            int2 p = payload[i];
            atomicAdd(&u.wdeg[(p.x >> 17) & 127], __int_as_float(p.y));
        }
        __syncthreads();
        if (tid < BNODES) {
            int v = blk * BNODES + tid;
            if (v < n) {
                float di = rsqrtf(u.wdeg[tid] + 1.0f);
                dinv[v] = di;
                selfn[v] = di * di;
            }
        }
    }
    __threadfence();
    grid.sync();

    // ---- phases 6-10: the 5 S-passes; pass 0 folds dinv[src] into weight ----
    for (int k = 0; k < 5; ++k) {
        if (tid < BNODES) u.sacc[tid] = make_float2(0.f, 0.f);
        __syncthreads();
        const float2* in = schain + (size_t)(k - 1) * n;  // unused when k==0
        float2* outv = schain + (size_t)k * n;
        int b0 = bstart[blk], b1e = bstart[blk + 1];
        for (int i = b0 + tid; i < b1e; i += TB) {
            int2 p = payload[i];
            int sidx = p.x & 0x1FFFF;
            int ld = (p.x >> 17) & 127;
            float nw, vx, vy;
            if (k == 0) {
                nw = __int_as_float(p.y) * dinv[sidx];
                payload[i].y = __float_as_int(nw);
                vx = x[sidx]; vy = 1.0f;
            } else {
                nw = __int_as_float(p.y);
                float2 iv = in[sidx];
                vx = iv.x; vy = iv.y;
            }
            atomicAdd(&u.sacc[ld].x, nw * vx);
            atomicAdd(&u.sacc[ld].y, nw * vy);
        }
        __syncthreads();
        if (tid < BNODES) {
            int v = blk * BNODES + tid;
            if (v < n) {
                float dv = dinv[v], sf = selfn[v];
                float ivx, ivy;
                if (k == 0) { ivx = x[v]; ivy = 1.0f; }
                else        { float2 iv = in[v]; ivx = iv.x; ivy = iv.y; }
                float2 a = u.sacc[tid];
                outv[v] = make_float2(fmaf(dv, a.x, sf * ivx), fmaf(dv, a.y, sf * ivy));
            }
        }
        __threadfence();
        grid.sync();
    }

    // ---- phase 11: rank-6 epilogue, grid-stride float4 ----
    {
        const float2* s1 = schain;
        const float2* s2 = schain + (size_t)n;
        const float2* s3 = schain + (size_t)2 * n;
        const float2* s4 = schain + (size_t)3 * n;
        const float2* s5 = schain + (size_t)4 * n;
        int total = n * 25;
        for (int q = blk * TB + tid; q < total; q += G * TB) {
            int v = q / 25;
            int j = (q - v * 25) * 4;
            float a5 = s5[v].x, u4v = s4[v].y, u3v = s3[v].y, u2v = s2[v].y, u1v = s1[v].y;
            float4 r;
            float* rp = (float*)&r;
#pragma unroll
            for (int kk = 0; kk < 4; ++kk) {
                int jj = j + kk;
                float val = b5[jj]
                          + a5  * coef[jj]
                          + u4v * coef[100 + jj]
                          + u3v * coef[200 + jj]
                          + u2v * coef[300 + jj]
                          + u1v * coef[400 + jj];
                rp[kk] = fmaxf(val, 0.0f);
            }
            out[q] = r;
        }
    }
}

// ==================== fallback: R4 multi-kernel path ====================

__global__ void k_chains(const float* __restrict__ W1, const float* __restrict__ b1,
                         const float* __restrict__ W2, const float* __restrict__ b2,
                         const float* __restrict__ W3, const float* __restrict__ b3,
                         const float* __restrict__ W4, const float* __restrict__ b4,
                         const float* __restrict__ W5, float* __restrict__ coef) {
    __shared__ float A[5][112];
    __shared__ float B[5][112];
    chains_block(W1, b1, W2, b2, W3, b3, W4, b4, W5, coef, A, B);
}

__global__ __launch_bounds__(TB) void k_final4(const float2* __restrict__ s1,
                                               const float2* __restrict__ s2,
                                               const float2* __restrict__ s3,
                                               const float2* __restrict__ s4,
                                               const float2* __restrict__ s5,
                                               const float* __restrict__ coef,
                                               const float* __restrict__ b5,
                                               float4* __restrict__ out, int n) {
    int q = blockIdx.x * TB + threadIdx.x;
    if (q >= n * 25) return;
    int v = q / 25;
    int j = (q - v * 25) * 4;
    float a5 = s5[v].x, u4 = s4[v].y, u3 = s3[v].y, u2 = s2[v].y, u1 = s1[v].y;
    float4 r;
    float* rp = (float*)&r;
#pragma unroll
    for (int k = 0; k < 4; ++k) {
        int jj = j + k;
        float val = b5[jj] + a5 * coef[jj] + u4 * coef[100 + jj] + u3 * coef[200 + jj]
                  + u2 * coef[300 + jj] + u1 * coef[400 + jj];
        rp[k] = fmaxf(val, 0.0f);
    }
    out[q] = r;
}

__global__ __launch_bounds__(TB) void k_hist(const int* __restrict__ dst,
                                             int* __restrict__ histmat,
                                             int E, int B, int chunk) {
    extern __shared__ int lhist[];
    for (int j = threadIdx.x; j < B; j += TB) lhist[j] = 0;
    __syncthreads();
    int blk = blockIdx.x;
    int e0 = blk * chunk, e1 = min(E, e0 + chunk);
    for (int i = e0 + threadIdx.x; i < e1; i += TB)
        atomicAdd(&lhist[dst[i] >> 7], 1);
    __syncthreads();
    for (int j = threadIdx.x; j < B; j += TB)
        histmat[j * CHB + blk] = lhist[j];
}

__global__ __launch_bounds__(TB) void k_scan1(int* __restrict__ cnt,
                                              int* __restrict__ bsum, int n) {
    __shared__ int tmp[TB];
    int i = blockIdx.x * TB + threadIdx.x;
    int v = (i < n) ? cnt[i] : 0;
    tmp[threadIdx.x] = v;
    __syncthreads();
    for (int off = 1; off < TB; off <<= 1) {
        int t = (threadIdx.x >= off) ? tmp[threadIdx.x - off] : 0;
        __syncthreads();
        tmp[threadIdx.x] += t;
        __syncthreads();
    }
    if (i < n) cnt[i] = tmp[threadIdx.x] - v;
    if (threadIdx.x == TB - 1) bsum[blockIdx.x] = tmp[TB - 1];
}

__global__ void k_scan2(int* __restrict__ bsum, int nb, int E) {
    __shared__ int tmp[1024];
    int x = threadIdx.x;
    int v = (x < nb) ? bsum[x] : 0;
    tmp[x] = v;
    __syncthreads();
    for (int off = 1; off < 1024; off <<= 1) {
        int t = (x >= off) ? tmp[x - off] : 0;
        __syncthreads();
        tmp[x] += t;
        __syncthreads();
    }
    if (x < nb) bsum[x] = tmp[x] - v;
    if (x == 0) bsum[nb] = E;
}

__global__ __launch_bounds__(TB) void k_scan3(int* __restrict__ histmat,
                                              const int* __restrict__ bsum, int n) {
    int i = blockIdx.x * TB + threadIdx.x;
    if (i < n) histmat[i] += bsum[i >> 8];
}

__global__ __launch_bounds__(TB) void k_bplace(const int* __restrict__ src,
                                               const int* __restrict__ dst,
                                               const float* __restrict__ w,
                                               const int* __restrict__ histmat,
                                               int2* __restrict__ payload,
                                               int E, int B, int chunk) {
    extern __shared__ int lcur[];
    int blk = blockIdx.x;
    for (int j = threadIdx.x; j < B; j += TB) lcur[j] = histmat[j * CHB + blk];
    __syncthreads();
    int e0 = blk * chunk, e1 = min(E, e0 + chunk);
    for (int i = e0 + threadIdx.x; i < e1; i += TB) {
        int d = dst[i];
        int j = d >> 7;
        int slot = atomicAdd(&lcur[j], 1);
        payload[slot] = make_int2(src[i] | ((d & 127) << 17), __float_as_int(w[i]));
    }
}

__global__ __launch_bounds__(TB) void k_bstats(const int* __restrict__ bstart,
                                               const int2* __restrict__ payload,
                                               float* __restrict__ dinv,
                                               float* __restrict__ selfn, int n) {
    __shared__ float wdeg[BNODES];
    int j = blockIdx.x;
    if (threadIdx.x < BNODES) wdeg[threadIdx.x] = 0.f;
    __syncthreads();
    int b0 = bstart[j], b1 = bstart[j + 1];
    for (int i = b0 + threadIdx.x; i < b1; i += TB) {
        int2 p = payload[i];
        atomicAdd(&wdeg[(p.x >> 17) & 127], __int_as_float(p.y));
    }
    __syncthreads();
    if (threadIdx.x < BNODES) {
        int v = j * BNODES + threadIdx.x;
        if (v < n) {
            float di = rsqrtf(wdeg[threadIdx.x] + 1.0f);
            dinv[v] = di;
            selfn[v] = di * di;
        }
    }
}

template <bool FIRST>
__global__ __launch_bounds__(TB) void k_bpass(const float* __restrict__ x,
                                              const float2* __restrict__ in,
                                              const int* __restrict__ bstart,
                                              int2* __restrict__ payload,
                                              const float* __restrict__ dinv,
                                              const float* __restrict__ selfn,
                                              float2* __restrict__ out, int n) {
    __shared__ float2 sacc[BNODES];
    int j = blockIdx.x;
    if (threadIdx.x < BNODES) sacc[threadIdx.x] = make_float2(0.f, 0.f);
    __syncthreads();
    int b0 = bstart[j], b1 = bstart[j + 1];
    for (int i = b0 + threadIdx.x; i < b1; i += TB) {
        int2 p = payload[i];
        int s = p.x & 0x1FFFF;
        int ld = (p.x >> 17) & 127;
        float nw, vx, vy;
        if (FIRST) {
            nw = __int_as_float(p.y) * dinv[s];
            payload[i] = make_int2(p.x, __float_as_int(nw));
            vx = x[s]; vy = 1.0f;
        } else {
            nw = __int_as_float(p.y);
            float2 iv = in[s];
            vx = iv.x; vy = iv.y;
        }
        atomicAdd(&sacc[ld].x, nw * vx);
        atomicAdd(&sacc[ld].y, nw * vy);
    }
    __syncthreads();
    if (threadIdx.x < BNODES) {
        int v = j * BNODES + threadIdx.x;
        if (v < n) {
            float dv = dinv[v], sf = selfn[v];
            float ivx, ivy;
            if (FIRST) { ivx = x[v]; ivy = 1.0f; }
            else       { float2 iv = in[v]; ivx = iv.x; ivy = iv.y; }
            float2 a = sacc[threadIdx.x];
            out[v] = make_float2(fmaf(dv, a.x, sf * ivx), fmaf(dv, a.y, sf * ivy));
        }
    }
}

// ==================== launch ====================

extern "C" void kernel_launch(void* const* d_in, const int* in_sizes, int n_in,
                              void* d_out, int out_size, void* d_ws, size_t ws_size,
                              hipStream_t stream) {
    const float* x  = (const float*)d_in[0];
    const int*   ei = (const int*)d_in[1];     // int32: [2, E] flattened
    const float* w  = (const float*)d_in[2];
    const float* W1 = (const float*)d_in[3];  const float* b1 = (const float*)d_in[4];
    const float* W2 = (const float*)d_in[5];  const float* b2 = (const float*)d_in[6];
    const float* W3 = (const float*)d_in[7];  const float* b3 = (const float*)d_in[8];
    const float* W4 = (const float*)d_in[9];  const float* b4 = (const float*)d_in[10];
    const float* W5 = (const float*)d_in[11]; const float* b5 = (const float*)d_in[12];

    int n = in_sizes[0];   // 100000
    int E = in_sizes[2];   // 1600000
    const int* src = ei;
    const int* dst = ei + E;

    int B = (n + BNODES - 1) / BNODES;   // 782
    int G = B;
    int chunk = (E + G - 1) / G;

    char* ws = (char*)d_ws;
    size_t off = 0;
    auto alloc = [&](size_t bytes) -> void* {
        void* p = ws + off;
        off += (bytes + 255) & ~(size_t)255;
        return p;
    };
    // mega layout (histmat is B*G; fallback needs only B*CHB which is smaller)
    size_t hm_elems = (size_t)B * ((G > CHB) ? G : CHB);
    int*   histmat = (int*)alloc(hm_elems * 4);
    int*   bstart  = (int*)alloc((size_t)(B + 1) * 4);
    float* dinv    = (float*)alloc((size_t)n * 4);
    float* selfn   = (float*)alloc((size_t)n * 4);
    float* coef    = (float*)alloc(512 * 4);
    int2*  payload = (int2*)alloc((size_t)E * 8);
    float2* schain = (float2*)alloc((size_t)5 * n * 8);
    float4* outp   = (float4*)d_out;

    void* args[] = {
        (void*)&x, (void*)&src, (void*)&dst, (void*)&w,
        (void*)&W1, (void*)&b1, (void*)&W2, (void*)&b2, (void*)&W3, (void*)&b3,
        (void*)&W4, (void*)&b4, (void*)&W5, (void*)&b5,
        (void*)&histmat, (void*)&bstart, (void*)&dinv, (void*)&selfn,
        (void*)&coef, (void*)&payload, (void*)&schain, (void*)&outp,
        (void*)&n, (void*)&E, (void*)&B, (void*)&chunk
    };
    hipError_t err = hipLaunchCooperativeKernel((const void*)k_mega, dim3(G), dim3(TB),
                                                args, 0, stream);
    if (err == hipSuccess) return;

    // ---- fallback: R4 multi-kernel path ----
    int chunkF = (E + CHB - 1) / CHB;
    int HM  = B * CHB;
    int nb1 = (HM + TB - 1) / TB;   // == B
    float2* s[5];
    for (int i = 0; i < 5; ++i) s[i] = schain + (size_t)i * n;
    const size_t ldsB = (size_t)B * 4;

    k_hist <<<CHB, TB, ldsB, stream>>>(dst, histmat, E, B, chunkF);
    k_scan1<<<nb1, TB, 0, stream>>>(histmat, bstart, HM);
    k_scan2<<<1, 1024, 0, stream>>>(bstart, nb1, E);
    k_scan3<<<nb1, TB, 0, stream>>>(histmat, bstart, HM);
    k_bplace<<<CHB, TB, ldsB, stream>>>(src, dst, w, histmat, payload, E, B, chunkF);
    k_bstats<<<B, TB, 0, stream>>>(bstart, payload, dinv, selfn, n);
    k_chains<<<1, 128, 0, stream>>>(W1, b1, W2, b2, W3, b3, W4, b4, W5, coef);
    k_bpass<true> <<<B, TB, 0, stream>>>(x, nullptr, bstart, payload, dinv, selfn, s[0], n);
    for (int k = 1; k < 5; ++k)
        k_bpass<false><<<B, TB, 0, stream>>>(nullptr, s[k - 1], bstart, payload, dinv, selfn, s[k], n);
    const int tot4 = n * 25;
    k_final4<<<(tot4 + TB - 1) / TB, TB, 0, stream>>>(s[0], s[1], s[2], s[3], s[4],
                                                      coef, b5, outp, n);
}

// Round 6
// 292.651 us; speedup vs baseline: 6.3043x; 6.3043x over previous
//
#include <hip/hip_runtime.h>

// GCN 5-layer, no inter-layer nonlinearity -> rank-6 outer product:
// out = relu( a5*c0^T + u4*c1^T + u3*c2^T + u2*c3^T + u1*c4^T + 1*b5^T )
// a_k = S^k x, u_k = S^k 1, S = D^-1/2 (A+I) D^-1/2, x is N x 1.
//
// R6: R5 proved grid.sync() costs ~160 us on gfx950 (10 syncs -> +1.6 ms idle,
// VALUBusy 0.5%). Back to stream-ordered kernels; cut launches 13 -> 8:
//  - scan2 folded into scan via last-block-done (agent-scope acq/rel atomics)
//  - scan3 folded into place cursor load
//  - k_chains runs as a spare block of k_hist
//  - final epilogue fused into pass 5 (per-bucket output tile)
// Rescaled iteration q_j = D^-1/2 S^j s0: passes use RAW edge weights
// (q'[v] = selfn[v]*(sum w*q[src] + q[v])) -> no dinv[src] gather and no
// payload rewrite in pass 0. Recover a5 = dinv*acc, u_j = q_j.y/dinv.

#define TB 256
#define BNODES 128          // nodes per bucket (dst>>7)
#define CHB 256             // chunk blocks for hist/place; == TB (scan row fits one segment)

// ---------------- weight-chain collapse (device helper) ----------------
// coef[0]=W1..W5 row0, coef[1]=b1*W2..W5, coef[2]=b2*W3..W5, coef[3]=b3*W4*W5, coef[4]=b4*W5
__device__ __forceinline__ void chains_block(
    const float* __restrict__ W1, const float* __restrict__ b1,
    const float* __restrict__ W2, const float* __restrict__ b2,
    const float* __restrict__ W3, const float* __restrict__ b3,
    const float* __restrict__ W4, const float* __restrict__ b4,
    const float* __restrict__ W5, float* __restrict__ coef,
    float (*A)[112], float (*Bm)[112]) {
    int t = threadIdx.x;
    if (t < 20) { A[0][t] = W1[t]; A[1][t] = b1[t]; }
    __syncthreads();
    if (t < 40) {
        for (int c = 0; c < 2; ++c) {
            float acc = 0.f;
            for (int k = 0; k < 20; ++k) acc += A[c][k] * W2[k * 40 + t];
            Bm[c][t] = acc;
        }
        Bm[2][t] = b2[t];
    }
    __syncthreads();
    if (t < 60) {
        for (int c = 0; c < 3; ++c) {
            float acc = 0.f;
            for (int k = 0; k < 40; ++k) acc += Bm[c][k] * W3[k * 60 + t];
            A[c][t] = acc;
        }
        A[3][t] = b3[t];
    }
    __syncthreads();
    if (t < 80) {
        for (int c = 0; c < 4; ++c) {
            float acc = 0.f;
            for (int k = 0; k < 60; ++k) acc += A[c][k] * W4[k * 80 + t];
            Bm[c][t] = acc;
        }
        Bm[4][t] = b4[t];
    }
    __syncthreads();
    if (t < 100) {
        for (int c = 0; c < 5; ++c) {
            float acc = 0.f;
            for (int k = 0; k < 80; ++k) acc += Bm[c][k] * W5[k * 100 + t];
            coef[c * 100 + t] = acc;
        }
    }
}

// ---------------- 1: histogram (+chains in spare block, +counter zero) ----------------
__global__ __launch_bounds__(TB) void k_hist(const int* __restrict__ dst,
                                             int* __restrict__ histmat,
                                             int* __restrict__ counter,
                                             const float* __restrict__ W1, const float* __restrict__ b1,
                                             const float* __restrict__ W2, const float* __restrict__ b2,
                                             const float* __restrict__ W3, const float* __restrict__ b3,
                                             const float* __restrict__ W4, const float* __restrict__ b4,
                                             const float* __restrict__ W5, float* __restrict__ coef,
                                             int E, int B, int chunk) {
    extern __shared__ char smem[];
    int blk = blockIdx.x;
    if (blk == CHB) {  // spare block: collapse the weight chain
        float (*A)[112]  = (float (*)[112])smem;
        float (*Bm)[112] = (float (*)[112])(smem + 5 * 112 * 4);
        chains_block(W1, b1, W2, b2, W3, b3, W4, b4, W5, coef, A, Bm);
        return;
    }
    int* lh = (int*)smem;
    if (blk == 0 && threadIdx.x == 0) *counter = 0;   // for k_scan's last-block detect
    for (int j = threadIdx.x; j < B; j += TB) lh[j] = 0;
    __syncthreads();
    int e0 = blk * chunk, e1 = min(E, e0 + chunk);
    for (int i = e0 + threadIdx.x; i < e1; i += TB)
        atomicAdd(&lh[dst[i] >> 7], 1);
    __syncthreads();
    for (int j = threadIdx.x; j < B; j += TB)
        histmat[j * CHB + blk] = lh[j];
}

// ---------------- 2: row scan + last-block bucket-total scan ----------------
__global__ __launch_bounds__(TB) void k_scan(int* __restrict__ histmat,
                                             int* __restrict__ btot,
                                             int* __restrict__ bstart,
                                             int* __restrict__ counter,
                                             int B, int E) {
    __shared__ int tmp[TB];
    __shared__ int isLast;
    int j = blockIdx.x;
    int i = threadIdx.x;
    int v = histmat[j * CHB + i];       // CHB == TB: one segment per row
    tmp[i] = v;
    __syncthreads();
    for (int o = 1; o < TB; o <<= 1) {
        int t = (i >= o) ? tmp[i - o] : 0;
        __syncthreads();
        tmp[i] += t;
        __syncthreads();
    }
    histmat[j * CHB + i] = tmp[i] - v;  // exclusive within bucket row
    if (i == TB - 1)
        __hip_atomic_store(&btot[j], tmp[TB - 1], __ATOMIC_RELEASE, __HIP_MEMORY_SCOPE_AGENT);
    __syncthreads();                    // barrier drains the store (vmcnt) before counter bump
    if (i == 0) {
        int old = __hip_atomic_fetch_add(counter, 1, __ATOMIC_ACQ_REL, __HIP_MEMORY_SCOPE_AGENT);
        isLast = (old == B - 1);
    }
    __syncthreads();
    if (isLast) {                       // exclusive scan of bucket totals -> bstart
        int carry = 0;
        for (int base = 0; base < B; base += TB) {
            int idx = base + i;
            int val = (idx < B)
                ? __hip_atomic_load(&btot[idx], __ATOMIC_ACQUIRE, __HIP_MEMORY_SCOPE_AGENT) : 0;
            tmp[i] = val;
            __syncthreads();
            for (int o = 1; o < TB; o <<= 1) {
                int t = (i >= o) ? tmp[i - o] : 0;
                __syncthreads();
                tmp[i] += t;
                __syncthreads();
            }
            if (idx < B) bstart[idx] = carry + tmp[i] - val;
            carry += tmp[TB - 1];
            __syncthreads();
        }
        if (i == 0) bstart[B] = E;
    }
}

// ---------------- 3: place (cursor = scanned row col + bucket start) ----------------
__global__ __launch_bounds__(TB) void k_bplace(const int* __restrict__ src,
                                               const int* __restrict__ dst,
                                               const float* __restrict__ w,
                                               const int* __restrict__ histmat,
                                               const int* __restrict__ bstart,
                                               int2* __restrict__ payload,
                                               int E, int B, int chunk) {
    extern __shared__ char smem[];
    int* lcur = (int*)smem;
    int blk = blockIdx.x;
    for (int j = threadIdx.x; j < B; j += TB)
        lcur[j] = histmat[j * CHB + blk] + bstart[j];
    __syncthreads();
    int e0 = blk * chunk, e1 = min(E, e0 + chunk);
    for (int i = e0 + threadIdx.x; i < e1; i += TB) {
        int d = dst[i];
        int j = d >> 7;
        int slot = atomicAdd(&lcur[j], 1);
        payload[slot] = make_int2(src[i] | ((d & 127) << 17), __float_as_int(w[i]));
    }
}

// ---------------- 4: per-bucket degree -> dinv, selfn, q0 = (dinv*x, dinv) ----------------
__global__ __launch_bounds__(TB) void k_bstats(const int* __restrict__ bstart,
                                               const int2* __restrict__ payload,
                                               const float* __restrict__ x,
                                               float* __restrict__ dinv,
                                               float* __restrict__ selfn,
                                               float2* __restrict__ q0, int n) {
    __shared__ float wdeg[BNODES];
    int j = blockIdx.x;
    if (threadIdx.x < BNODES) wdeg[threadIdx.x] = 0.f;
    __syncthreads();
    int b0 = bstart[j], b1 = bstart[j + 1];
    for (int i = b0 + threadIdx.x; i < b1; i += TB) {
        int2 p = payload[i];
        atomicAdd(&wdeg[(p.x >> 17) & 127], __int_as_float(p.y));
    }
    __syncthreads();
    if (threadIdx.x < BNODES) {
        int v = j * BNODES + threadIdx.x;
        if (v < n) {
            float di = rsqrtf(wdeg[threadIdx.x] + 1.0f);  // deg >= 0, +1 self loop
            dinv[v] = di;
            selfn[v] = di * di;
            q0[v] = make_float2(di * x[v], di);           // channels: (x, ones), pre-scaled
        }
    }
}

// ---------------- 5..9: passes; LAST fuses the rank-6 epilogue ----------------
template <bool LAST>
__global__ __launch_bounds__(TB) void k_pass(const int* __restrict__ bstart,
                                             const int2* __restrict__ payload,
                                             const float2* __restrict__ qin,  // q_{k-1} (== q4 when LAST)
                                             const float* __restrict__ dinv,
                                             const float* __restrict__ selfn,
                                             float2* __restrict__ qout,       // !LAST
                                             const float2* __restrict__ q1,
                                             const float2* __restrict__ q2,
                                             const float2* __restrict__ q3,
                                             const float* __restrict__ coef,
                                             const float* __restrict__ b5,
                                             float4* __restrict__ out, int n) {
    __shared__ float2 sacc[BNODES];
    int j = blockIdx.x;
    int tid = threadIdx.x;
    if (tid < BNODES) sacc[tid] = make_float2(0.f, 0.f);
    __syncthreads();
    int b0 = bstart[j], b1 = bstart[j + 1];
    for (int i = b0 + tid; i < b1; i += TB) {
        int2 p = payload[i];
        int sidx = p.x & 0x1FFFF;
        int ld = (p.x >> 17) & 127;
        float wv = __int_as_float(p.y);
        float2 qv = qin[sidx];
        atomicAdd(&sacc[ld].x, wv * qv.x);
        atomicAdd(&sacc[ld].y, wv * qv.y);
    }
    __syncthreads();
    if constexpr (!LAST) {
        if (tid < BNODES) {
            int v = j * BNODES + tid;
            if (v < n) {
                float2 a = sacc[tid];
                float2 qv = qin[v];
                float sf = selfn[v];
                qout[v] = make_float2(sf * (a.x + qv.x), sf * (a.y + qv.y));
            }
        }
    } else {
        __shared__ float scoef[500];
        __shared__ float sb5[100];
        __shared__ float snode[BNODES * 5];  // a5, u4, u3, u2, u1 per node
        for (int i = tid; i < 500; i += TB) scoef[i] = coef[i];
        for (int i = tid; i < 100; i += TB) sb5[i] = b5[i];
        if (tid < BNODES) {
            int v = j * BNODES + tid;
            if (v < n) {
                float2 a = sacc[tid];
                float2 qv = qin[v];                 // q4[v]
                float dv = dinv[v];
                float inv = 1.0f / dv;              // = sqrt(deg)
                snode[tid * 5 + 0] = dv * (a.x + qv.x);   // a5 = dinv * (Aq4 + q4).x
                snode[tid * 5 + 1] = qv.y * inv;          // u4
                snode[tid * 5 + 2] = q3[v].y * inv;       // u3
                snode[tid * 5 + 3] = q2[v].y * inv;       // u2
                snode[tid * 5 + 4] = q1[v].y * inv;       // u1
            }
        }
        __syncthreads();
        int base_v = j * BNODES;
        int nv = min(BNODES, n - base_v);
        int total4 = nv * 25;                       // 100 floats per node as float4
        for (int q = tid; q < total4; q += TB) {
            int lv = q / 25;
            int col4 = q - lv * 25;
            int c0 = col4 * 4;
            float a5 = snode[lv * 5 + 0], u4 = snode[lv * 5 + 1], u3 = snode[lv * 5 + 2],
                  u2 = snode[lv * 5 + 3], u1 = snode[lv * 5 + 4];
            float4 r;
            float* rp = (float*)&r;
#pragma unroll
            for (int kk = 0; kk < 4; ++kk) {
                int c = c0 + kk;
                rp[kk] = fmaxf(sb5[c] + a5 * scoef[c] + u4 * scoef[100 + c] + u3 * scoef[200 + c]
                               + u2 * scoef[300 + c] + u1 * scoef[400 + c], 0.f);
            }
            out[(size_t)(base_v + lv) * 25 + col4] = r;
        }
    }
}

// ==================== launch ====================

extern "C" void kernel_launch(void* const* d_in, const int* in_sizes, int n_in,
                              void* d_out, int out_size, void* d_ws, size_t ws_size,
                              hipStream_t stream) {
    const float* x  = (const float*)d_in[0];
    const int*   ei = (const int*)d_in[1];     // int32: [2, E] flattened
    const float* w  = (const float*)d_in[2];
    const float* W1 = (const float*)d_in[3];  const float* b1 = (const float*)d_in[4];
    const float* W2 = (const float*)d_in[5];  const float* b2 = (const float*)d_in[6];
    const float* W3 = (const float*)d_in[7];  const float* b3 = (const float*)d_in[8];
    const float* W4 = (const float*)d_in[9];  const float* b4 = (const float*)d_in[10];
    const float* W5 = (const float*)d_in[11]; const float* b5 = (const float*)d_in[12];

    const int n = in_sizes[0];   // 100000
    const int E = in_sizes[2];   // 1600000
    const int* src = ei;
    const int* dst = ei + E;

    const int B = (n + BNODES - 1) / BNODES;   // 782 buckets
    const int chunk = (E + CHB - 1) / CHB;     // 6250 edges per chunk block

    char* ws = (char*)d_ws;
    size_t off = 0;
    auto alloc = [&](size_t bytes) -> void* {
        void* p = ws + off;
        off += (bytes + 255) & ~(size_t)255;
        return p;
    };
    int*   histmat = (int*)alloc((size_t)B * CHB * 4);
    int*   btot    = (int*)alloc((size_t)B * 4);
    int*   bstart  = (int*)alloc((size_t)(B + 1) * 4);
    int*   counter = (int*)alloc(256);
    float* dinv    = (float*)alloc((size_t)n * 4);
    float* selfn   = (float*)alloc((size_t)n * 4);
    float* coef    = (float*)alloc(512 * 4);
    int2*  payload = (int2*)alloc((size_t)E * 8);
    float2* q[5];
    for (int i = 0; i < 5; ++i) q[i] = (float2*)alloc((size_t)n * 8);

    const size_t ldsHist  = ((size_t)B * 4 > 4480) ? (size_t)B * 4 : 4480;  // hist bins vs chains scratch
    const size_t ldsPlace = (size_t)B * 4;

    k_hist<<<CHB + 1, TB, ldsHist, stream>>>(dst, histmat, counter,
                                             W1, b1, W2, b2, W3, b3, W4, b4, W5, coef,
                                             E, B, chunk);
    k_scan<<<B, TB, 0, stream>>>(histmat, btot, bstart, counter, B, E);
    k_bplace<<<CHB, TB, ldsPlace, stream>>>(src, dst, w, histmat, bstart, payload, E, B, chunk);
    k_bstats<<<B, TB, 0, stream>>>(bstart, payload, x, dinv, selfn, q[0], n);

    // q[k] = D^-1 (A+I) q[k-1]; last pass fuses epilogue
    for (int k = 1; k < 5; ++k)
        k_pass<false><<<B, TB, 0, stream>>>(bstart, payload, q[k - 1], dinv, selfn, q[k],
                                            nullptr, nullptr, nullptr, nullptr, nullptr,
                                            nullptr, n);
    k_pass<true><<<B, TB, 0, stream>>>(bstart, payload, q[4], dinv, selfn, nullptr,
                                       q[1], q[2], q[3], coef, b5, (float4*)d_out, n);
}